// Round 3
// baseline (609.568 us; speedup 1.0000x reference)
//
#include <hip/hip_runtime.h>
#include <stdint.h>

// Problem constants (fixed by reference setup_inputs)
#define BB 32
#define NN 131072            // 2^17
#define BN (BB * NN)         // 4,194,304 = 2^22
#define TT 32768             // NUM_POINTS_TARGET
#define CELL 0.05f
#define HBITS 23
#define HSIZE (1 << HBITS)   // 8,388,608 slots
#define HMASK (HSIZE - 1)
#define EMPTY64 0xFFFFFFFFFFFFFFFFULL
#define IDXMASK 0x3FFFFFULL  // low 22 bits = point index

// Output layout in d_out (floats), in return order:
// y_sel [32,32768,3], idx_out [32,32768,2], mask_sel [32,32768],
// ul_idx [BN], ul_idx_inv [BN]
#define Y_OFF   0
#define IDX_OFF (BB * TT * 3)                    // 3,145,728
#define MSK_OFF (IDX_OFF + BB * TT * 2)          // 5,242,880
#define ULI_OFF (MSK_OFF + BB * TT)              // 6,291,456
#define ULV_OFF (ULI_OFF + BN)                   // 10,485,760

#define SCAN_TPB 256
#define SCAN_EPT 16
#define SCAN_EPB (SCAN_TPB * SCAN_EPT)           // 4096
#define SCAN_NBLK (BN / SCAN_EPB)                // 1024

__global__ void k_init(int* scal) {
    scal[0] = 0x7FFFFFFF;  // min
    scal[1] = 0x80000000;  // max
    scal[2] = 0;           // total uniques
}

// Global min/max over all 3*BN quantized coords
__global__ void k_minmax(const float* __restrict__ x, int* scal) {
    int tid = blockIdx.x * blockDim.x + threadIdx.x;
    int stride = gridDim.x * blockDim.x;
    int lmin = 0x7FFFFFFF, lmax = (int)0x80000000;
    for (int i = tid; i < 3 * BN; i += stride) {
        int g = (int)rintf(x[i] / CELL);   // round half-to-even like jnp.round
        lmin = min(lmin, g);
        lmax = max(lmax, g);
    }
    for (int off = 32; off > 0; off >>= 1) {
        lmin = min(lmin, __shfl_down(lmin, off));
        lmax = max(lmax, __shfl_down(lmax, off));
    }
    if ((threadIdx.x & 63) == 0) {
        atomicMin(&scal[0], lmin);
        atomicMax(&scal[1], lmax);
    }
}

// Voxel key per point; insert into packed 64-bit hash:
// slot = (key << 22) | min_flat_idx. CAS-first: ~1 atomic per point.
__global__ void k_insert(const float* __restrict__ x, const int* __restrict__ scal,
                         unsigned long long* __restrict__ slots,
                         int* __restrict__ slotArr) {
    int i = blockIdx.x * blockDim.x + threadIdx.x;
    if (i >= BN) return;
    int ming = scal[0];
    int gs = scal[1] - ming + 2;
    int g0 = (int)rintf(x[3 * i + 0] / CELL) - ming;
    int g1 = (int)rintf(x[3 * i + 1] / CELL) - ming;
    int g2 = (int)rintf(x[3 * i + 2] / CELL) - ming;
    int b = i >> 17;  // i / NN
    unsigned int key = (unsigned int)(gs * (gs * g0 + g1) + g2 + gs * gs * gs * b); // <2^29
    unsigned long long packed = ((unsigned long long)key << 22) | (unsigned int)i;
    unsigned int s = (key * 2654435761u) >> (32 - HBITS);
    for (;;) {
        unsigned long long cur = atomicCAS(&slots[s], EMPTY64, packed);
        if (cur == EMPTY64) break;                 // claimed fresh slot
        if ((unsigned int)(cur >> 22) == key) {    // same voxel already present
            if (packed < cur) atomicMin(&slots[s], packed);  // rare
            break;
        }
        s = (s + 1) & HMASK;                       // different key: probe on
    }
    slotArr[i] = (int)s;
}

// Scan pass A: resolve first-occurrence position per point; flag bitmask;
// block partial sums of flags
__global__ void k_scanA(const int* __restrict__ slotArr,
                        const unsigned long long* __restrict__ slots,
                        int* __restrict__ pfirst, unsigned short* __restrict__ fmask,
                        int* __restrict__ bsums) {
    int t = threadIdx.x;
    int base = blockIdx.x * SCAN_EPB + t * SCAN_EPT;
    int s = 0;
    unsigned int bits = 0;
    for (int e = 0; e < SCAN_EPT; e++) {
        int i = base + e;
        int p = (int)(slots[slotArr[i]] & IDXMASK);
        pfirst[i] = p;
        int f = (p == i);
        bits |= (unsigned int)f << e;
        s += f;
    }
    fmask[blockIdx.x * SCAN_TPB + t] = (unsigned short)bits;
    __shared__ int sh[SCAN_TPB];
    sh[t] = s;
    __syncthreads();
    for (int off = SCAN_TPB / 2; off > 0; off >>= 1) {
        if (t < off) sh[t] += sh[t + off];
        __syncthreads();
    }
    if (t == 0) bsums[blockIdx.x] = sh[0];
}

// Scan pass B: exclusive scan of 1024 block sums; store grand total
__global__ void k_scanB(int* __restrict__ bsums, int* __restrict__ scal, int nb) {
    __shared__ int sh[1024];
    int t = threadIdx.x;
    int v = (t < nb) ? bsums[t] : 0;
    sh[t] = v;
    __syncthreads();
    for (int off = 1; off < 1024; off <<= 1) {
        int add = (t >= off) ? sh[t - off] : 0;
        __syncthreads();
        sh[t] += add;
        __syncthreads();
    }
    if (t < nb) bsums[t] = sh[t] - v;       // exclusive
    if (t == nb - 1) scal[2] = sh[t];       // total uniques U
}

// Scan pass C: write exclusive scan per element; scatter ul_idx_inv[rank] = pos
__global__ void k_scanC(const unsigned short* __restrict__ fmask,
                        const int* __restrict__ bsums,
                        int* __restrict__ scanArr, float* __restrict__ ulinv) {
    int t = threadIdx.x;
    int base = blockIdx.x * SCAN_EPB + t * SCAN_EPT;
    unsigned int bits = fmask[blockIdx.x * SCAN_TPB + t];
    int s = __popc(bits);
    __shared__ int sh[SCAN_TPB];
    sh[t] = s;
    __syncthreads();
    int v = s;
    for (int off = 1; off < SCAN_TPB; off <<= 1) {
        int add = (t >= off) ? sh[t - off] : 0;
        __syncthreads();
        sh[t] += add;
        __syncthreads();
    }
    int prefix = bsums[blockIdx.x] + sh[t] - v;  // exclusive prefix for this thread
    for (int e = 0; e < SCAN_EPT; e++) {
        int i = base + e;
        int f = (bits >> e) & 1;
        scanArr[i] = prefix;
        if (f) ulinv[prefix] = (float)i;
        prefix += f;
    }
}

// Fused: ul_idx gather + ul_idx_inv tail pad + stable top-k partition + output gather
__global__ void k_select(const float* __restrict__ x, const int* __restrict__ pfirst,
                         const int* __restrict__ scanArr,
                         const unsigned short* __restrict__ fmask,
                         const int* __restrict__ scal,
                         float* __restrict__ ysel, float* __restrict__ idxout,
                         float* __restrict__ msel, float* __restrict__ uli,
                         float* __restrict__ ulinv) {
    int i = blockIdx.x * blockDim.x + threadIdx.x;
    if (i >= BN) return;
    uli[i] = (float)scanArr[pfirst[i]];      // appearance rank of i's voxel
    int U = scal[2];
    if (i >= U) ulinv[i] = (float)BN;        // sentinel tail
    int b = i >> 17;
    int j = i & (NN - 1);
    int base = scanArr[b << 17];
    int ones_before = scanArr[i] - base;
    int cnt1 = ((b == BB - 1) ? U : scanArr[(b + 1) << 17]) - base;
    int flag = (fmask[i >> 4] >> (i & 15)) & 1;
    int pos = flag ? ones_before : cnt1 + (j - ones_before);
    if (pos < TT) {
        float y0 = CELL * rintf(x[3 * i + 0] / CELL);
        float y1 = CELL * rintf(x[3 * i + 1] / CELL);
        float y2 = CELL * rintf(x[3 * i + 2] / CELL);
        int yo = (b * TT + pos) * 3;
        ysel[yo + 0] = y0;
        ysel[yo + 1] = y1;
        ysel[yo + 2] = y2;
        int io = (b * TT + pos) * 2;
        idxout[io + 0] = (float)b;
        idxout[io + 1] = (float)j;
        msel[b * TT + pos] = flag ? 1.0f : 0.0f;
    }
}

extern "C" void kernel_launch(void* const* d_in, const int* in_sizes, int n_in,
                              void* d_out, int out_size, void* d_ws, size_t ws_size,
                              hipStream_t stream) {
    const float* x = (const float*)d_in[0];
    float* out = (float*)d_out;
    char* ws = (char*)d_ws;

    // ws layout (bytes): scalars 256 | slotArr BN*4 | pfirst BN*4 | scanArr BN*4
    //                    | bsums 4096 | fmask BN/16*2 | slots64 HSIZE*8
    int* scal    = (int*)ws;
    int* slotArr = (int*)(ws + 256);
    int* pfirst  = slotArr + BN;
    int* scanArr = pfirst + BN;
    int* bsums   = scanArr + BN;
    unsigned short* fmask = (unsigned short*)(bsums + 1024);
    unsigned long long* slots = (unsigned long long*)((char*)fmask + (BN / 16) * 2);

    hipMemsetAsync(slots, 0xFF, (size_t)HSIZE * 8, stream);  // all EMPTY64
    k_init<<<1, 1, 0, stream>>>(scal);
    k_minmax<<<1024, 256, 0, stream>>>(x, scal);
    k_insert<<<BN / 256, 256, 0, stream>>>(x, scal, slots, slotArr);
    k_scanA<<<SCAN_NBLK, SCAN_TPB, 0, stream>>>(slotArr, slots, pfirst, fmask, bsums);
    k_scanB<<<1, 1024, 0, stream>>>(bsums, scal, SCAN_NBLK);
    k_scanC<<<SCAN_NBLK, SCAN_TPB, 0, stream>>>(fmask, bsums, scanArr, out + ULV_OFF);
    k_select<<<BN / 256, 256, 0, stream>>>(x, pfirst, scanArr, fmask, scal,
                                           out + Y_OFF, out + IDX_OFF, out + MSK_OFF,
                                           out + ULI_OFF, out + ULV_OFF);
}

// Round 4
// 476.470 us; speedup vs baseline: 1.2793x; 1.2793x over previous
//
#include <hip/hip_runtime.h>
#include <stdint.h>

// Problem constants (fixed by reference setup_inputs)
#define BB 32
#define NN 131072            // 2^17 points per batch
#define BN (BB * NN)         // 4,194,304 = 2^22
#define TT 32768             // NUM_POINTS_TARGET
#define CELL 0.05f
#define TBITS 18
#define TSIZE (1 << TBITS)   // 262,144 slots per batch table (2 MB)
#define TMASK (TSIZE - 1)
#define EMPTY64 0xFFFFFFFFFFFFFFFFULL
#define LIMASK 0x1FFFFULL    // low 17 bits = local point index

// Output layout in d_out (floats), in return order:
// y_sel [32,32768,3], idx_out [32,32768,2], mask_sel [32,32768],
// ul_idx [BN], ul_idx_inv [BN]
#define Y_OFF   0
#define IDX_OFF (BB * TT * 3)                    // 3,145,728
#define MSK_OFF (IDX_OFF + BB * TT * 2)          // 5,242,880
#define ULI_OFF (MSK_OFF + BB * TT)              // 6,291,456
#define ULV_OFF (ULI_OFF + BN)                   // 10,485,760

#define SCAN_TPB 256
#define SCAN_EPT 16
#define SCAN_EPB (SCAN_TPB * SCAN_EPT)           // 4096
#define SCAN_NBLK (BN / SCAN_EPB)                // 1024 (32 per batch)

__global__ void k_init(int* scal) {
    scal[0] = 0x7FFFFFFF;  // min
    scal[1] = 0x80000000;  // max
    scal[2] = 0;           // total uniques
}

// Global min/max over all 3*BN quantized coords
__global__ void k_minmax(const float* __restrict__ x, int* scal) {
    int tid = blockIdx.x * blockDim.x + threadIdx.x;
    int stride = gridDim.x * blockDim.x;
    int lmin = 0x7FFFFFFF, lmax = (int)0x80000000;
    for (int i = tid; i < 3 * BN; i += stride) {
        int g = (int)rintf(x[i] / CELL);   // round half-to-even like jnp.round
        lmin = min(lmin, g);
        lmax = max(lmax, g);
    }
    for (int off = 32; off > 0; off >>= 1) {
        lmin = min(lmin, __shfl_down(lmin, off));
        lmax = max(lmax, __shfl_down(lmax, off));
    }
    if ((threadIdx.x & 63) == 0) {
        atomicMin(&scal[0], lmin);
        atomicMax(&scal[1], lmax);
    }
}

// Per-batch hash insert. batch = blockIdx % 32 => all blocks of batch b land on
// XCD b%8 (blockIdx%8 dispatch heuristic), so each XCD's L2 serves only its
// 4 x 2MB tables. Load-first probe; atomic only when needed (values in a slot
// are monotonically decreasing, so stale L1 reads are always >= current).
__global__ void k_insert(const float* __restrict__ x, const int* __restrict__ scal,
                         unsigned long long* __restrict__ slots,
                         int* __restrict__ slotArr) {
    int blk = blockIdx.x;
    int b = blk & 31;
    int chunk = blk >> 5;
    int li = (chunk << 8) + threadIdx.x;   // local idx in batch, < 2^17
    int i = (b << 17) + li;                // flat idx
    int ming = scal[0];
    int gs = scal[1] - ming + 2;
    int g0 = (int)rintf(x[3 * i + 0] / CELL) - ming;
    int g1 = (int)rintf(x[3 * i + 1] / CELL) - ming;
    int g2 = (int)rintf(x[3 * i + 2] / CELL) - ming;
    unsigned int key = (unsigned int)(gs * (gs * g0 + g1) + g2);  // < 2^24 (batch-local)
    unsigned long long packed = ((unsigned long long)key << 17) | (unsigned int)li;
    unsigned long long* tab = slots + ((size_t)b << TBITS);
    unsigned int s = (key * 2654435761u) >> (32 - TBITS);
    for (;;) {
        unsigned long long cur = tab[s];           // plain load (L1/L2 hit path)
        if (cur == EMPTY64) {
            unsigned long long old = atomicCAS(&tab[s], EMPTY64, packed);
            if (old == EMPTY64) break;             // claimed fresh slot
            cur = old;                             // lost race: fall through
        }
        if ((unsigned int)(cur >> 17) == key) {    // voxel already present
            if (packed < cur) atomicMin(&tab[s], packed);  // rare
            break;
        }
        s = (s + 1) & TMASK;                       // different key: probe on
    }
    slotArr[i] = (int)s;
}

// Scan pass A: resolve first-occurrence position per point; flag bitmask;
// block partial sums of flags. Same %32 swizzle so table gathers stay local.
__global__ void k_scanA(const int* __restrict__ slotArr,
                        const unsigned long long* __restrict__ slots,
                        int* __restrict__ pfirst, unsigned short* __restrict__ fmask,
                        int* __restrict__ bsums) {
    int blk = blockIdx.x;
    int b = blk & 31;
    int chunk = blk >> 5;                  // < 32
    int fbid = (b << 5) + chunk;           // flat-order block id for bsums/fmask
    int t = threadIdx.x;
    int base = (b << 17) + chunk * SCAN_EPB + t * SCAN_EPT;  // flat
    const unsigned long long* tab = slots + ((size_t)b << TBITS);
    int bbase = b << 17;
    int s = 0;
    unsigned int bits = 0;
    for (int e = 0; e < SCAN_EPT; e++) {
        int i = base + e;
        int p = (int)(tab[slotArr[i]] & LIMASK) + bbase;
        pfirst[i] = p;
        int f = (p == i);
        bits |= (unsigned int)f << e;
        s += f;
    }
    fmask[fbid * SCAN_TPB + t] = (unsigned short)bits;
    __shared__ int sh[SCAN_TPB];
    sh[t] = s;
    __syncthreads();
    for (int off = SCAN_TPB / 2; off > 0; off >>= 1) {
        if (t < off) sh[t] += sh[t + off];
        __syncthreads();
    }
    if (t == 0) bsums[fbid] = sh[0];
}

// Scan pass B: exclusive scan of 1024 block sums; store grand total
__global__ void k_scanB(int* __restrict__ bsums, int* __restrict__ scal, int nb) {
    __shared__ int sh[1024];
    int t = threadIdx.x;
    int v = (t < nb) ? bsums[t] : 0;
    sh[t] = v;
    __syncthreads();
    for (int off = 1; off < 1024; off <<= 1) {
        int add = (t >= off) ? sh[t - off] : 0;
        __syncthreads();
        sh[t] += add;
        __syncthreads();
    }
    if (t < nb) bsums[t] = sh[t] - v;       // exclusive
    if (t == nb - 1) scal[2] = sh[t];       // total uniques U
}

// Scan pass C: write exclusive scan per element; scatter ul_idx_inv[rank] = pos
__global__ void k_scanC(const unsigned short* __restrict__ fmask,
                        const int* __restrict__ bsums,
                        int* __restrict__ scanArr, float* __restrict__ ulinv) {
    int t = threadIdx.x;
    int base = blockIdx.x * SCAN_EPB + t * SCAN_EPT;
    unsigned int bits = fmask[blockIdx.x * SCAN_TPB + t];
    int s = __popc(bits);
    __shared__ int sh[SCAN_TPB];
    sh[t] = s;
    __syncthreads();
    int v = s;
    for (int off = 1; off < SCAN_TPB; off <<= 1) {
        int add = (t >= off) ? sh[t - off] : 0;
        __syncthreads();
        sh[t] += add;
        __syncthreads();
    }
    int prefix = bsums[blockIdx.x] + sh[t] - v;  // exclusive prefix for this thread
    for (int e = 0; e < SCAN_EPT; e++) {
        int i = base + e;
        int f = (bits >> e) & 1;
        scanArr[i] = prefix;
        if (f) ulinv[prefix] = (float)i;
        prefix += f;
    }
}

// Fused: ul_idx gather + ul_idx_inv tail pad + stable top-k partition + output
// gather. %32 swizzle keeps the scanArr[pfirst[i]] gather in the batch's
// 512 KB scanArr window on the right XCD.
__global__ void k_select(const float* __restrict__ x, const int* __restrict__ pfirst,
                         const int* __restrict__ scanArr,
                         const unsigned short* __restrict__ fmask,
                         const int* __restrict__ scal,
                         float* __restrict__ ysel, float* __restrict__ idxout,
                         float* __restrict__ msel, float* __restrict__ uli,
                         float* __restrict__ ulinv) {
    int blk = blockIdx.x;
    int b = blk & 31;
    int chunk = blk >> 5;
    int j = (chunk << 8) + threadIdx.x;      // local idx in batch
    int i = (b << 17) + j;                   // flat
    uli[i] = (float)scanArr[pfirst[i]];      // appearance rank of i's voxel
    int U = scal[2];
    if (i >= U) ulinv[i] = (float)BN;        // sentinel tail
    int base = scanArr[b << 17];
    int ones_before = scanArr[i] - base;
    int cnt1 = ((b == BB - 1) ? U : scanArr[(b + 1) << 17]) - base;
    int flag = (fmask[i >> 4] >> (i & 15)) & 1;
    int pos = flag ? ones_before : cnt1 + (j - ones_before);
    if (pos < TT) {
        float y0 = CELL * rintf(x[3 * i + 0] / CELL);
        float y1 = CELL * rintf(x[3 * i + 1] / CELL);
        float y2 = CELL * rintf(x[3 * i + 2] / CELL);
        int yo = (b * TT + pos) * 3;
        ysel[yo + 0] = y0;
        ysel[yo + 1] = y1;
        ysel[yo + 2] = y2;
        int io = (b * TT + pos) * 2;
        idxout[io + 0] = (float)b;
        idxout[io + 1] = (float)j;
        msel[b * TT + pos] = flag ? 1.0f : 0.0f;
    }
}

extern "C" void kernel_launch(void* const* d_in, const int* in_sizes, int n_in,
                              void* d_out, int out_size, void* d_ws, size_t ws_size,
                              hipStream_t stream) {
    const float* x = (const float*)d_in[0];
    float* out = (float*)d_out;
    char* ws = (char*)d_ws;

    // ws layout (bytes): scalars 256 | slotArr BN*4 | pfirst BN*4 | scanArr BN*4
    //                    | bsums 4096 | fmask BN/16*2 | slots 32*TSIZE*8 (64 MB)
    int* scal    = (int*)ws;
    int* slotArr = (int*)(ws + 256);
    int* pfirst  = slotArr + BN;
    int* scanArr = pfirst + BN;
    int* bsums   = scanArr + BN;
    unsigned short* fmask = (unsigned short*)(bsums + 1024);
    unsigned long long* slots = (unsigned long long*)((char*)fmask + (BN / 16) * 2);

    hipMemsetAsync(slots, 0xFF, (size_t)BB * TSIZE * 8, stream);  // all EMPTY64
    k_init<<<1, 1, 0, stream>>>(scal);
    k_minmax<<<1024, 256, 0, stream>>>(x, scal);
    k_insert<<<BN / 256, 256, 0, stream>>>(x, scal, slots, slotArr);
    k_scanA<<<SCAN_NBLK, SCAN_TPB, 0, stream>>>(slotArr, slots, pfirst, fmask, bsums);
    k_scanB<<<1, 1024, 0, stream>>>(bsums, scal, SCAN_NBLK);
    k_scanC<<<SCAN_NBLK, SCAN_TPB, 0, stream>>>(fmask, bsums, scanArr, out + ULV_OFF);
    k_select<<<BN / 256, 256, 0, stream>>>(x, pfirst, scanArr, fmask, scal,
                                           out + Y_OFF, out + IDX_OFF, out + MSK_OFF,
                                           out + ULI_OFF, out + ULV_OFF);
}